// Round 8
// baseline (336.538 us; speedup 1.0000x reference)
//
#include <hip/hip_runtime.h>
#include <cstdint>

typedef __attribute__((ext_vector_type(8))) short bf16x8;
typedef __attribute__((ext_vector_type(4))) float f32x4;

#define DEV static __device__ __forceinline__

DEV unsigned short f2bf(float f) {
  unsigned int u = __builtin_bit_cast(unsigned int, f);
  u += 0x7FFFu + ((u >> 16) & 1u);
  return (unsigned short)(u >> 16);
}
#if __has_builtin(__builtin_amdgcn_cvt_pk_bf16_f32)
DEV unsigned int pkbf(float a, float b) {
  auto v = __builtin_amdgcn_cvt_pk_bf16_f32(a, b);
  return __builtin_bit_cast(unsigned int, v);
}
#else
DEV unsigned int pkbf(float a, float b) {
  return (unsigned int)f2bf(a) | ((unsigned int)f2bf(b) << 16);
}
#endif
#if __has_builtin(__builtin_amdgcn_exp2f)
#define EXP2(x) __builtin_amdgcn_exp2f(x)
#else
#define EXP2(x) exp2f(x)
#endif

DEV void async_copy16(const unsigned short* g, unsigned short* l) {
  __builtin_amdgcn_global_load_lds(
      (const __attribute__((address_space(1))) unsigned int*)(uintptr_t)g,
      (__attribute__((address_space(3))) unsigned int*)(uintptr_t)l,
      16, 0, 0);
}

// ---------------------------------------------------------------------------
// Convert wq,wk,wv (1M elem each, fp32) -> bf16 at ws elem [0,3M).
// 3072 blocks x 256 threads, one float4 each.
// ---------------------------------------------------------------------------
__global__ __launch_bounds__(256) void cvt_w3(
    const float* __restrict__ w0, const float* __restrict__ w1,
    const float* __restrict__ w2, unsigned short* __restrict__ out)
{
  int id = blockIdx.x * 256 + threadIdx.x;      // 0 .. 786431
  int m = id >> 18;                             // 0..2
  int off = (id & 0x3FFFF) << 2;
  const float* src = m == 0 ? w0 : m == 1 ? w1 : w2;
  float4 v = *(const float4*)(src + off);
  uint2 o;
  o.x = pkbf(v.x, v.y);
  o.y = pkbf(v.z, v.w);
  *(uint2*)(out + (((size_t)m) << 20) + off) = o;
}

// ---------------------------------------------------------------------------
// Hybrid fused QKV projection: A = X fp32 (cvt-staged), B = W bf16 (async
// global_load_lds). z = blockIdx.z selects {Q,K,V}; W_z at wbase + z<<20.
// z<2 -> scatter [bh][s][64]; z==2 -> V^T [bh][hd][s] (b64 packed).
// ---------------------------------------------------------------------------
__global__ __launch_bounds__(256) void gemm_qkv_hyb(
    const float* __restrict__ xq, const float* __restrict__ xkv,
    const unsigned short* __restrict__ wbase,
    const float* __restrict__ bq, const float* __restrict__ bk,
    const float* __restrict__ bv,
    unsigned short* __restrict__ outq, unsigned short* __restrict__ outk,
    unsigned short* __restrict__ outvT)
{
  constexpr int K = 1024;
  __shared__ unsigned short As[128 * 32];
  __shared__ unsigned short Bs[128 * 32];
  const int z = blockIdx.z;
  const float* X = (z == 0) ? xq : xkv;
  const unsigned short* Wb = wbase + (((size_t)z) << 20);
  const float* bias = (z == 0) ? bq : (z == 1) ? bk : bv;

  const int tid = threadIdx.x;
  const int mBase = blockIdx.y * 128, nBase = blockIdx.x * 128;
  const int wave = tid >> 6, lane = tid & 63;
  const int quad = lane >> 4, l16 = lane & 15;
  const int wm = (wave >> 1) << 6, wn = (wave & 1) << 6;

  f32x4 acc[4][4] = {};

  for (int k0 = 0; k0 < K; k0 += 32) {
    // B: async bf16 staging
#pragma unroll
    for (int i = 0; i < 2; ++i) {
      int e = i * 2048 + tid * 8;
      int row = e >> 5, col = e & 31;
      async_copy16(Wb + (size_t)(nBase + row) * K + (k0 + col), &Bs[e]);
    }
    // A: fp32 load, cvt, LDS store
    float4 xv[2][2];
#pragma unroll
    for (int i = 0; i < 2; ++i) {
      int e = i * 2048 + tid * 8;
      int row = e >> 5, col = e & 31;
      const float* px = X + (size_t)(mBase + row) * K + (k0 + col);
      xv[i][0] = *(const float4*)px;
      xv[i][1] = *(const float4*)(px + 4);
    }
#pragma unroll
    for (int i = 0; i < 2; ++i) {
      int e = i * 2048 + tid * 8;
      uint4 xo;
      xo.x = pkbf(xv[i][0].x, xv[i][0].y); xo.y = pkbf(xv[i][0].z, xv[i][0].w);
      xo.z = pkbf(xv[i][1].x, xv[i][1].y); xo.w = pkbf(xv[i][1].z, xv[i][1].w);
      *(uint4*)&As[e] = xo;
    }
    __syncthreads();
    bf16x8 af[4], bff[4];
#pragma unroll
    for (int t = 0; t < 4; ++t) {
      af[t]  = *(const bf16x8*)&As[(wm + t * 16 + l16) * 32 + quad * 8];
      bff[t] = *(const bf16x8*)&Bs[(wn + t * 16 + l16) * 32 + quad * 8];
    }
#pragma unroll
    for (int mt = 0; mt < 4; ++mt)
#pragma unroll
      for (int nt = 0; nt < 4; ++nt)
        acc[mt][nt] = __builtin_amdgcn_mfma_f32_16x16x32_bf16(af[mt], bff[nt], acc[mt][nt], 0, 0, 0);
    __syncthreads();
  }

  if (z < 2) {
    unsigned short* out = z ? outk : outq;
#pragma unroll
    for (int nt = 0; nt < 4; ++nt) {
      int n = nBase + wn + nt * 16 + l16;
      float bv2 = bias[n];
      int h = n >> 6, hd = n & 63;
#pragma unroll
      for (int mt = 0; mt < 4; ++mt) {
#pragma unroll
        for (int j = 0; j < 4; ++j) {
          int m = mBase + wm + mt * 16 + quad * 4 + j;
          int b = m >> 11, s = m & 2047;
          out[(((size_t)(b * 16 + h) * 2048 + s) << 6) + hd] = f2bf(acc[mt][nt][j] + bv2);
        }
      }
    }
  } else {
#pragma unroll
    for (int nt = 0; nt < 4; ++nt) {
      int n = nBase + wn + nt * 16 + l16;
      float bv2 = bias[n];
      int h = n >> 6, hd = n & 63;
#pragma unroll
      for (int mt = 0; mt < 4; ++mt) {
        int m0 = mBase + wm + mt * 16 + quad * 4;
        int b = m0 >> 11, s = m0 & 2047;
        uint2 o;
        o.x = pkbf(acc[mt][nt][0] + bv2, acc[mt][nt][1] + bv2);
        o.y = pkbf(acc[mt][nt][2] + bv2, acc[mt][nt][3] + bv2);
        *(uint2*)&outvT[(((size_t)(b * 16 + h) * 64 + hd) << 11) + s] = o;
      }
    }
  }
}

// ---------------------------------------------------------------------------
// RoPE interleaved, in-place on q and k [bh][s][64] (bf16).
// Q additionally scaled by 0.125*log2(e): softmax runs in exp2 domain.
// ---------------------------------------------------------------------------
__global__ __launch_bounds__(256) void rope_kernel(unsigned short* __restrict__ q,
                                                   unsigned short* __restrict__ k)
{
  int idx = blockIdx.x * 256 + threadIdx.x;
  int tsel = idx >> 21;
  int r = idx & 0x1FFFFF;
  int i = r & 31;
  int srow = r >> 5;          // bh*2048 + s
  int s = srow & 2047;
  unsigned short* p = (tsel ? k : q) + (((size_t)srow) << 6) + (i << 1);
  float inv_freq = exp2f(-(float)i * 0.4152410118609203f);
  float ang = (float)s * inv_freq;
  float sn, cs;
  sincosf(ang, &sn, &cs);
  unsigned int pv = *(const unsigned int*)p;
  float xe = __builtin_bit_cast(float, (pv & 0xFFFFu) << 16);
  float xo = __builtin_bit_cast(float, pv & 0xFFFF0000u);
  float qs = tsel ? 1.0f : 0.18033688011112042f;  // 0.125*log2(e)
  float re = (xe * cs - xo * sn) * qs;
  float ro = (xe * sn + xo * cs) * qs;
  *(unsigned int*)p = pkbf(re, ro);
}

// ---------------------------------------------------------------------------
// Flash attention v5: v4 (S^T, static softmax, 32 q-rows/wave, grid 512)
// + load/compute overlap: V loads for the CURRENT tile issue before QK
// compute; K loads for the NEXT tile issue right after QK consumes kc.
// Each load gets several hundred cycles of MFMA+softmax cover.
// Q,K: [bh][s][64] (Q pre-scaled); VT: [bh][hd][s]; ctx: [4096][1024] bf16.
// ---------------------------------------------------------------------------
__global__ __launch_bounds__(256, 2) void attn_v5(
    const unsigned short* __restrict__ Qg,
    const unsigned short* __restrict__ Kg,
    const unsigned short* __restrict__ VT,
    unsigned short* __restrict__ ctx)
{
  constexpr int LDP = 72;
  __shared__ unsigned short Ps[4 * 32 * LDP];
  const int tid = threadIdx.x, wave = tid >> 6, lane = tid & 63;
  const int quad = lane >> 4, l16 = lane & 15;
  const int bh = blockIdx.x & 31;        // XCD-swizzle
  const int qt = blockIdx.x >> 5;
  const int q0 = qt * 128 + wave * 32;
  const unsigned short* Qb = Qg + ((size_t)bh << 17);
  const unsigned short* Kb = Kg + ((size_t)bh << 17);
  const unsigned short* Vb = VT + ((size_t)bh << 17);
  unsigned short* Pw = &Ps[wave * 32 * LDP];

  // Q b-frags, register-resident: [n=q][k=d]
  bf16x8 qf[2][2];
#pragma unroll
  for (int mq = 0; mq < 2; ++mq)
#pragma unroll
    for (int kd = 0; kd < 2; ++kd)
      qf[mq][kd] = *(const bf16x8*)(Qb + (size_t)(q0 + mq * 16 + l16) * 64 + kd * 32 + quad * 8);

  // preload K tile 0
  bf16x8 kc[4][2];
#pragma unroll
  for (int tk = 0; tk < 4; ++tk)
#pragma unroll
    for (int kd = 0; kd < 2; ++kd)
      kc[tk][kd] = *(const bf16x8*)(Kb + (size_t)(tk * 16 + l16) * 64 + kd * 32 + quad * 8);

  f32x4 oacc[4][2] = {};                 // O^T tiles [th(hd)][mq(q)]
  float lacc[2] = { 0.f, 0.f };

  for (int kv0 = 0; kv0 < 2048; kv0 += 64) {
    // --- issue V loads for THIS tile (consumed at tile end) ---
    bf16x8 vc[4][2];
#pragma unroll
    for (int th = 0; th < 4; ++th)
#pragma unroll
      for (int ks = 0; ks < 2; ++ks)
        vc[th][ks] = *(const bf16x8*)(Vb + (size_t)(th * 16 + l16) * 2048 + kv0 + ks * 32 + quad * 8);

    // --- S^T = K·Q^T with preloaded kc ---
    f32x4 st[4][2] = {};
#pragma unroll
    for (int tk = 0; tk < 4; ++tk)
#pragma unroll
      for (int kd = 0; kd < 2; ++kd)
#pragma unroll
        for (int mq = 0; mq < 2; ++mq)
          st[tk][mq] = __builtin_amdgcn_mfma_f32_16x16x32_bf16(kc[tk][kd], qf[mq][kd], st[tk][mq], 0, 0, 0);

    // --- prefetch NEXT K tile into kc (wrap-clamped; last iter harmless) ---
    {
      int nkv = (kv0 + 64) & 2047;
#pragma unroll
      for (int tk = 0; tk < 4; ++tk)
#pragma unroll
        for (int kd = 0; kd < 2; ++kd)
          kc[tk][kd] = *(const bf16x8*)(Kb + (size_t)(nkv + tk * 16 + l16) * 64 + kd * 32 + quad * 8);
    }

    // --- static softmax: p = exp2(st), per-lane l accumulate, pack to LDS ---
#pragma unroll
    for (int mq = 0; mq < 2; ++mq)
#pragma unroll
      for (int tk = 0; tk < 4; ++tk) {
#pragma unroll
        for (int jr = 0; jr < 4; ++jr) {
          float p = EXP2(st[tk][mq][jr]);
          st[tk][mq][jr] = p;
          lacc[mq] += p;
        }
        uint2 o;
        o.x = pkbf(st[tk][mq][0], st[tk][mq][1]);
        o.y = pkbf(st[tk][mq][2], st[tk][mq][3]);
        *(uint2*)&Pw[(mq * 16 + l16) * LDP + tk * 16 + quad * 4] = o;
      }

    // --- O^T += V^T·P^T with vc ---
#pragma unroll
    for (int ks = 0; ks < 2; ++ks) {
      bf16x8 pf[2];
#pragma unroll
      for (int mq = 0; mq < 2; ++mq)
        pf[mq] = *(const bf16x8*)&Pw[(mq * 16 + l16) * LDP + ks * 32 + quad * 8];
#pragma unroll
      for (int th = 0; th < 4; ++th)
#pragma unroll
        for (int mq = 0; mq < 2; ++mq)
          oacc[th][mq] = __builtin_amdgcn_mfma_f32_16x16x32_bf16(vc[th][ks], pf[mq], oacc[th][mq], 0, 0, 0);
    }
  }

  // --- epilogue: one cross-lane l reduce, normalize, write ctx ---
  const int b = bh >> 4, h = bh & 15;
#pragma unroll
  for (int mq = 0; mq < 2; ++mq) {
    float l = lacc[mq];
    l += __shfl_xor(l, 16);
    l += __shfl_xor(l, 32);
    float rinv = 1.0f / l;
    int s = q0 + mq * 16 + l16;
#pragma unroll
    for (int th = 0; th < 4; ++th) {
      uint2 o;
      o.x = pkbf(oacc[th][mq][0] * rinv, oacc[th][mq][1] * rinv);
      o.y = pkbf(oacc[th][mq][2] * rinv, oacc[th][mq][3] * rinv);
      *(uint2*)&ctx[((size_t)(b * 2048 + s) << 10) + h * 64 + th * 16 + quad * 4] = o;
    }
  }
}

// ---------------------------------------------------------------------------
// O-projection hybrid: A = ctx bf16 (async), B = wo fp32 (cvt-staged).
// 128x128 tile, grid (8,32). fp32 output to d_out.
// ---------------------------------------------------------------------------
__global__ __launch_bounds__(256) void gemm_o_hyb(
    const unsigned short* __restrict__ X,
    const float* __restrict__ W,
    const float* __restrict__ bias,
    float* __restrict__ out)
{
  constexpr int K = 1024;
  __shared__ unsigned short As[128 * 32];
  __shared__ unsigned short Bs[128 * 32];
  const int tid = threadIdx.x;
  const int mBase = blockIdx.y * 128;
  const int nBase = blockIdx.x * 128;
  const int wave = tid >> 6, lane = tid & 63;
  const int quad = lane >> 4, l16 = lane & 15;
  const int wm = (wave >> 1) << 6, wn = (wave & 1) << 6;

  f32x4 acc[4][4] = {};

  for (int k0 = 0; k0 < K; k0 += 32) {
    // A: async bf16
#pragma unroll
    for (int i = 0; i < 2; ++i) {
      int e = i * 2048 + tid * 8;
      int row = e >> 5, col = e & 31;
      async_copy16(X + (size_t)(mBase + row) * K + (k0 + col), &As[e]);
    }
    // B: fp32 cvt-staged
    float4 wv[2][2];
#pragma unroll
    for (int i = 0; i < 2; ++i) {
      int e = i * 2048 + tid * 8;
      int row = e >> 5, col = e & 31;
      const float* pw = W + (size_t)(nBase + row) * K + (k0 + col);
      wv[i][0] = *(const float4*)pw;
      wv[i][1] = *(const float4*)(pw + 4);
    }
#pragma unroll
    for (int i = 0; i < 2; ++i) {
      int e = i * 2048 + tid * 8;
      uint4 wo;
      wo.x = pkbf(wv[i][0].x, wv[i][0].y); wo.y = pkbf(wv[i][0].z, wv[i][0].w);
      wo.z = pkbf(wv[i][1].x, wv[i][1].y); wo.w = pkbf(wv[i][1].z, wv[i][1].w);
      *(uint4*)&Bs[e] = wo;
    }
    __syncthreads();
    bf16x8 af[4], bff[4];
#pragma unroll
    for (int t = 0; t < 4; ++t) {
      af[t]  = *(const bf16x8*)&As[(wm + t * 16 + l16) * 32 + quad * 8];
      bff[t] = *(const bf16x8*)&Bs[(wn + t * 16 + l16) * 32 + quad * 8];
    }
#pragma unroll
    for (int mt = 0; mt < 4; ++mt)
#pragma unroll
      for (int nt = 0; nt < 4; ++nt)
        acc[mt][nt] = __builtin_amdgcn_mfma_f32_16x16x32_bf16(af[mt], bff[nt], acc[mt][nt], 0, 0, 0);
    __syncthreads();
  }

#pragma unroll
  for (int nt = 0; nt < 4; ++nt) {
    int n = nBase + wn + nt * 16 + l16;
    float bv = bias[n];
#pragma unroll
    for (int mt = 0; mt < 4; ++mt) {
#pragma unroll
      for (int j = 0; j < 4; ++j) {
        int m = mBase + wm + mt * 16 + quad * 4 + j;
        out[((size_t)m << 10) + n] = acc[mt][nt][j] + bv;
      }
    }
  }
}

// ---------------------------------------------------------------------------
// ws layout (32 MB total, elements of 2 bytes; 1M = 1<<20 elem = 2 MB):
//   [0, 3M)   : wq,wk,wv bf16 (dead after QKV gemm)
//   [0, 4M)   : ctx bf16 (written by attn, after weights are dead)
//   [4M, 8M)  : q   [8M,12M): k   [12M,16M): vT
// ---------------------------------------------------------------------------
extern "C" void kernel_launch(void* const* d_in, const int* in_sizes, int n_in,
                              void* d_out, int out_size, void* d_ws, size_t ws_size,
                              hipStream_t stream) {
  const float* x_q  = (const float*)d_in[0];
  const float* x_kv = (const float*)d_in[1];
  const float* wq   = (const float*)d_in[2];
  const float* bq   = (const float*)d_in[3];
  const float* wk   = (const float*)d_in[4];
  const float* bk   = (const float*)d_in[5];
  const float* wv   = (const float*)d_in[6];
  const float* bv   = (const float*)d_in[7];
  const float* wo   = (const float*)d_in[8];
  const float* bo   = (const float*)d_in[9];

  unsigned short* base = (unsigned short*)d_ws;
  unsigned short* ctx = base;
  unsigned short* q   = base + (4u << 20);
  unsigned short* k   = base + (8u << 20);
  unsigned short* vT  = base + (12u << 20);
  float* out = (float*)d_out;

  cvt_w3<<<3072, 256, 0, stream>>>(wq, wk, wv, base);
  gemm_qkv_hyb<<<dim3(8, 32, 3), 256, 0, stream>>>(x_q, x_kv, base,
                                                   bq, bk, bv, q, k, vT);
  rope_kernel<<<16384, 256, 0, stream>>>(q, k);
  attn_v5<<<512, 256, 0, stream>>>(q, k, vT, ctx);
  gemm_o_hyb<<<dim3(8, 32), 256, 0, stream>>>(ctx, wo, bo, out);
}

// Round 9
// 270.580 us; speedup vs baseline: 1.2438x; 1.2438x over previous
//
#include <hip/hip_runtime.h>
#include <cstdint>

typedef __attribute__((ext_vector_type(8))) short bf16x8;
typedef __attribute__((ext_vector_type(4))) float f32x4;

#define DEV static __device__ __forceinline__

DEV unsigned short f2bf(float f) {
  unsigned int u = __builtin_bit_cast(unsigned int, f);
  u += 0x7FFFu + ((u >> 16) & 1u);
  return (unsigned short)(u >> 16);
}
#if __has_builtin(__builtin_amdgcn_cvt_pk_bf16_f32)
DEV unsigned int pkbf(float a, float b) {
  auto v = __builtin_amdgcn_cvt_pk_bf16_f32(a, b);
  return __builtin_bit_cast(unsigned int, v);
}
#else
DEV unsigned int pkbf(float a, float b) {
  return (unsigned int)f2bf(a) | ((unsigned int)f2bf(b) << 16);
}
#endif
#if __has_builtin(__builtin_amdgcn_exp2f)
#define EXP2(x) __builtin_amdgcn_exp2f(x)
#else
#define EXP2(x) exp2f(x)
#endif
DEV float bfl(unsigned int u) { return __builtin_bit_cast(float, u << 16); }
DEV float bfh(unsigned int u) { return __builtin_bit_cast(float, u & 0xFFFF0000u); }

DEV void async_copy16(const unsigned short* g, unsigned short* l) {
  __builtin_amdgcn_global_load_lds(
      (const __attribute__((address_space(1))) unsigned int*)(uintptr_t)g,
      (__attribute__((address_space(3))) unsigned int*)(uintptr_t)l,
      16, 0, 0);
}

// ---------------------------------------------------------------------------
// cvt8: fp32 -> bf16 for wq,wk,wv,wo (ws elem [0,4M)) and x_q,x_kv
// (d_out bf16 view: xqb@[0,4M), xkvb@[4M,8M)). 3M threads, float4 each.
// ---------------------------------------------------------------------------
__global__ __launch_bounds__(256) void cvt8(
    const float* __restrict__ w0, const float* __restrict__ w1,
    const float* __restrict__ w2, const float* __restrict__ w3,
    const float* __restrict__ x0, const float* __restrict__ x1,
    unsigned short* __restrict__ wsb, unsigned short* __restrict__ xb)
{
  int id = blockIdx.x * 256 + threadIdx.x;      // 0 .. 3M-1
  const float* src;
  unsigned short* dp;
  int off;
  if (id < (1 << 20)) {
    int m = id >> 18;
    off = (id & 0x3FFFF) << 2;
    src = m == 0 ? w0 : m == 1 ? w1 : m == 2 ? w2 : w3;
    dp = wsb + (((size_t)m) << 20) + off;
  } else {
    int id2 = id - (1 << 20);
    int m = id2 >> 20;
    off = (id2 & 0xFFFFF) << 2;
    src = m ? x1 : x0;
    dp = xb + (((size_t)m) << 22) + off;
  }
  float4 v = *(const float4*)(src + off);
  uint2 o;
  o.x = pkbf(v.x, v.y);
  o.y = pkbf(v.z, v.w);
  *(uint2*)dp = o;
}

// ---------------------------------------------------------------------------
// All-bf16 fused QKV projection (m97: both operands async global_load_lds).
// z selects {Q,K,V}; W_z at wbase + z<<20. z<2 -> [bh][s][64];
// z==2 -> V^T [bh][hd][s] (b64 packed).
// ---------------------------------------------------------------------------
__global__ __launch_bounds__(256) void gemm_qkv_bf(
    const unsigned short* __restrict__ xqb,
    const unsigned short* __restrict__ xkvb,
    const unsigned short* __restrict__ wbase,
    const float* __restrict__ bq, const float* __restrict__ bk,
    const float* __restrict__ bv,
    unsigned short* __restrict__ outq, unsigned short* __restrict__ outk,
    unsigned short* __restrict__ outvT)
{
  constexpr int K = 1024;
  __shared__ unsigned short As[128 * 32];
  __shared__ unsigned short Bs[128 * 32];
  const int z = blockIdx.z;
  const unsigned short* X = (z == 0) ? xqb : xkvb;
  const unsigned short* Wb = wbase + (((size_t)z) << 20);
  const float* bias = (z == 0) ? bq : (z == 1) ? bk : bv;

  const int tid = threadIdx.x;
  const int mBase = blockIdx.y * 128, nBase = blockIdx.x * 128;
  const int wave = tid >> 6, lane = tid & 63;
  const int quad = lane >> 4, l16 = lane & 15;
  const int wm = (wave >> 1) << 6, wn = (wave & 1) << 6;

  f32x4 acc[4][4] = {};

  for (int k0 = 0; k0 < K; k0 += 32) {
#pragma unroll
    for (int i = 0; i < 2; ++i) {
      int e = i * 2048 + tid * 8;
      int row = e >> 5, col = e & 31;
      async_copy16(X + (size_t)(mBase + row) * K + (k0 + col), &As[e]);
      async_copy16(Wb + (size_t)(nBase + row) * K + (k0 + col), &Bs[e]);
    }
    __syncthreads();
    bf16x8 af[4], bff[4];
#pragma unroll
    for (int t = 0; t < 4; ++t) {
      af[t]  = *(const bf16x8*)&As[(wm + t * 16 + l16) * 32 + quad * 8];
      bff[t] = *(const bf16x8*)&Bs[(wn + t * 16 + l16) * 32 + quad * 8];
    }
#pragma unroll
    for (int mt = 0; mt < 4; ++mt)
#pragma unroll
      for (int nt = 0; nt < 4; ++nt)
        acc[mt][nt] = __builtin_amdgcn_mfma_f32_16x16x32_bf16(af[mt], bff[nt], acc[mt][nt], 0, 0, 0);
    __syncthreads();
  }

  if (z < 2) {
    unsigned short* out = z ? outk : outq;
#pragma unroll
    for (int nt = 0; nt < 4; ++nt) {
      int n = nBase + wn + nt * 16 + l16;
      float bv2 = bias[n];
      int h = n >> 6, hd = n & 63;
#pragma unroll
      for (int mt = 0; mt < 4; ++mt) {
#pragma unroll
        for (int j = 0; j < 4; ++j) {
          int m = mBase + wm + mt * 16 + quad * 4 + j;
          int b = m >> 11, s = m & 2047;
          out[(((size_t)(b * 16 + h) * 2048 + s) << 6) + hd] = f2bf(acc[mt][nt][j] + bv2);
        }
      }
    }
  } else {
#pragma unroll
    for (int nt = 0; nt < 4; ++nt) {
      int n = nBase + wn + nt * 16 + l16;
      float bv2 = bias[n];
      int h = n >> 6, hd = n & 63;
#pragma unroll
      for (int mt = 0; mt < 4; ++mt) {
        int m0 = mBase + wm + mt * 16 + quad * 4;
        int b = m0 >> 11, s = m0 & 2047;
        uint2 o;
        o.x = pkbf(acc[mt][nt][0] + bv2, acc[mt][nt][1] + bv2);
        o.y = pkbf(acc[mt][nt][2] + bv2, acc[mt][nt][3] + bv2);
        *(uint2*)&outvT[(((size_t)(b * 16 + h) * 64 + hd) << 11) + s] = o;
      }
    }
  }
}

// ---------------------------------------------------------------------------
// RoPE interleaved, in-place on q and k [bh][s][64] (bf16).
// Q additionally scaled by 0.125*log2(e): softmax runs in exp2 domain.
// ---------------------------------------------------------------------------
__global__ __launch_bounds__(256) void rope_kernel(unsigned short* __restrict__ q,
                                                   unsigned short* __restrict__ k)
{
  int idx = blockIdx.x * 256 + threadIdx.x;
  int tsel = idx >> 21;
  int r = idx & 0x1FFFFF;
  int i = r & 31;
  int srow = r >> 5;          // bh*2048 + s
  int s = srow & 2047;
  unsigned short* p = (tsel ? k : q) + (((size_t)srow) << 6) + (i << 1);
  float inv_freq = exp2f(-(float)i * 0.4152410118609203f);
  float ang = (float)s * inv_freq;
  float sn, cs;
  sincosf(ang, &sn, &cs);
  unsigned int pv = *(const unsigned int*)p;
  float xe = bfl(pv);
  float xo = bfh(pv);
  float qs = tsel ? 1.0f : 0.18033688011112042f;  // 0.125*log2(e)
  float re = (xe * cs - xo * sn) * qs;
  float ro = (xe * sn + xo * cs) * qs;
  *(unsigned int*)p = pkbf(re, ro);
}

// ---------------------------------------------------------------------------
// Flash attention v6: static softmax (exp2 domain) + kv-SPLIT (exact with
// static softmax: partials just add). Grid 1024 = bh(32) x qt(16) x kvs(2)
// -> 4 blocks/CU. Block-level LDS staging of K and V^T tiles (pad 72).
// Writes unnormalized partial O (bf16) and partial l (fp32).
// ---------------------------------------------------------------------------
__global__ __launch_bounds__(256) void attn_v6(
    const unsigned short* __restrict__ Qg,
    const unsigned short* __restrict__ Kg,
    const unsigned short* __restrict__ VT,
    unsigned short* __restrict__ Opart,   // [kvs][4096][1024] bf16
    float* __restrict__ lbuf)             // [kvs][32][2048]
{
  constexpr int LDW = 72;
  __shared__ unsigned short Ks[64 * LDW];
  __shared__ unsigned short Vs[64 * LDW];
  __shared__ unsigned short Ps[4 * 32 * LDW];
  const int tid = threadIdx.x, wave = tid >> 6, lane = tid & 63;
  const int quad = lane >> 4, l16 = lane & 15;
  const int bh = blockIdx.x & 31;            // XCD-swizzle
  const int qt = (blockIdx.x >> 5) & 15;
  const int kvs = blockIdx.x >> 9;           // 0/1
  const int q0 = qt * 128 + wave * 32;
  const unsigned short* Qb = Qg + ((size_t)bh << 17);
  const unsigned short* Kb = Kg + ((size_t)bh << 17);
  const unsigned short* Vb = VT + ((size_t)bh << 17);
  unsigned short* Pw = &Ps[wave * 32 * LDW];

  bf16x8 qf[2][2];
#pragma unroll
  for (int mq = 0; mq < 2; ++mq)
#pragma unroll
    for (int kd = 0; kd < 2; ++kd)
      qf[mq][kd] = *(const bf16x8*)(Qb + (size_t)(q0 + mq * 16 + l16) * 64 + kd * 32 + quad * 8);

  f32x4 oacc[4][2] = {};                     // [th(hd)][mq(q)]
  float lacc[2] = { 0.f, 0.f };

  const int kvbeg = kvs << 10;
  for (int kv0 = kvbeg; kv0 < kvbeg + 1024; kv0 += 64) {
    // --- stage K tile [kv][64] and V^T tile [hd][64] (coalesced 16B) ---
#pragma unroll
    for (int i = 0; i < 2; ++i) {
      int c = i * 256 + tid;
      int row = c >> 3, col8 = (c & 7) << 3;
      *(uint4*)&Ks[row * LDW + col8] =
          *(const uint4*)(Kb + (size_t)(kv0 + row) * 64 + col8);
      *(uint4*)&Vs[row * LDW + col8] =
          *(const uint4*)(Vb + (size_t)row * 2048 + kv0 + col8);
    }
    __syncthreads();

    // --- S^T = K·Q^T ---
    f32x4 st[4][2] = {};
#pragma unroll
    for (int tk = 0; tk < 4; ++tk)
#pragma unroll
      for (int kd = 0; kd < 2; ++kd) {
        bf16x8 kf = *(const bf16x8*)&Ks[(tk * 16 + l16) * LDW + kd * 32 + quad * 8];
#pragma unroll
        for (int mq = 0; mq < 2; ++mq)
          st[tk][mq] = __builtin_amdgcn_mfma_f32_16x16x32_bf16(kf, qf[mq][kd], st[tk][mq], 0, 0, 0);
      }

    // --- static softmax: p = exp2(st), per-lane l, pack P to per-wave LDS ---
#pragma unroll
    for (int mq = 0; mq < 2; ++mq)
#pragma unroll
      for (int tk = 0; tk < 4; ++tk) {
#pragma unroll
        for (int jr = 0; jr < 4; ++jr) {
          float p = EXP2(st[tk][mq][jr]);
          st[tk][mq][jr] = p;
          lacc[mq] += p;
        }
        uint2 o;
        o.x = pkbf(st[tk][mq][0], st[tk][mq][1]);
        o.y = pkbf(st[tk][mq][2], st[tk][mq][3]);
        *(uint2*)&Pw[(mq * 16 + l16) * LDW + tk * 16 + quad * 4] = o;
      }

    // --- O^T += V^T·P^T ---
#pragma unroll
    for (int ks = 0; ks < 2; ++ks) {
      bf16x8 pf[2];
#pragma unroll
      for (int mq = 0; mq < 2; ++mq)
        pf[mq] = *(const bf16x8*)&Pw[(mq * 16 + l16) * LDW + ks * 32 + quad * 8];
#pragma unroll
      for (int th = 0; th < 4; ++th) {
        bf16x8 vf = *(const bf16x8*)&Vs[(th * 16 + l16) * LDW + ks * 32 + quad * 8];
#pragma unroll
        for (int mq = 0; mq < 2; ++mq)
          oacc[th][mq] = __builtin_amdgcn_mfma_f32_16x16x32_bf16(vf, pf[mq], oacc[th][mq], 0, 0, 0);
      }
    }
    __syncthreads();
  }

  // --- epilogue: write partial l (quad 0) and unnormalized partial O ---
  const int b = bh >> 4, h = bh & 15;
  unsigned short* Od = Opart + (((size_t)kvs) << 22);
#pragma unroll
  for (int mq = 0; mq < 2; ++mq) {
    float l = lacc[mq];
    l += __shfl_xor(l, 16);
    l += __shfl_xor(l, 32);
    int s = q0 + mq * 16 + l16;
    if (quad == 0)
      lbuf[(kvs * 32 + bh) * 2048 + s] = l;
#pragma unroll
    for (int th = 0; th < 4; ++th) {
      uint2 o;
      o.x = pkbf(oacc[th][mq][0], oacc[th][mq][1]);
      o.y = pkbf(oacc[th][mq][2], oacc[th][mq][3]);
      *(uint2*)&Od[((size_t)(b * 2048 + s) << 10) + h * 64 + th * 16 + quad * 4] = o;
    }
  }
}

// ---------------------------------------------------------------------------
// Combine the two kv-split partials: ctx = (OA + OB) / (lA + lB).
// One thread per uint (2 bf16 elems); 2M threads.
// ---------------------------------------------------------------------------
__global__ __launch_bounds__(256) void combine_kernel(
    const unsigned short* __restrict__ Opart, const float* __restrict__ lbuf,
    unsigned short* __restrict__ ctx)
{
  int idx = blockIdx.x * 256 + threadIdx.x;   // 0 .. 2M-1
  int m = idx >> 9;                           // row 0..4095
  int c2 = idx & 511;
  int b = m >> 11, s = m & 2047;
  int h = c2 >> 5;
  int bh = b * 16 + h;
  float la = lbuf[bh * 2048 + s];
  float lb = lbuf[(32 + bh) * 2048 + s];
  float r = 1.0f / (la + lb);
  unsigned int ua = ((const unsigned int*)Opart)[idx];
  unsigned int ub = ((const unsigned int*)Opart)[(1u << 21) + idx];
  float o0 = (bfl(ua) + bfl(ub)) * r;
  float o1 = (bfh(ua) + bfh(ub)) * r;
  ((unsigned int*)ctx)[idx] = pkbf(o0, o1);
}

// ---------------------------------------------------------------------------
// O-projection: both operands bf16, both async-staged. fp32 out + bias.
// ---------------------------------------------------------------------------
__global__ __launch_bounds__(256) void gemm_o_bf(
    const unsigned short* __restrict__ X,
    const unsigned short* __restrict__ Wb,
    const float* __restrict__ bias,
    float* __restrict__ out)
{
  constexpr int K = 1024;
  __shared__ unsigned short As[128 * 32];
  __shared__ unsigned short Bs[128 * 32];
  const int tid = threadIdx.x;
  const int mBase = blockIdx.y * 128, nBase = blockIdx.x * 128;
  const int wave = tid >> 6, lane = tid & 63;
  const int quad = lane >> 4, l16 = lane & 15;
  const int wm = (wave >> 1) << 6, wn = (wave & 1) << 6;

  f32x4 acc[4][4] = {};

  for (int k0 = 0; k0 < K; k0 += 32) {
#pragma unroll
    for (int i = 0; i < 2; ++i) {
      int e = i * 2048 + tid * 8;
      int row = e >> 5, col = e & 31;
      async_copy16(X + (size_t)(mBase + row) * K + (k0 + col), &As[e]);
      async_copy16(Wb + (size_t)(nBase + row) * K + (k0 + col), &Bs[e]);
    }
    __syncthreads();
    bf16x8 af[4], bff[4];
#pragma unroll
    for (int t = 0; t < 4; ++t) {
      af[t]  = *(const bf16x8*)&As[(wm + t * 16 + l16) * 32 + quad * 8];
      bff[t] = *(const bf16x8*)&Bs[(wn + t * 16 + l16) * 32 + quad * 8];
    }
#pragma unroll
    for (int mt = 0; mt < 4; ++mt)
#pragma unroll
      for (int nt = 0; nt < 4; ++nt)
        acc[mt][nt] = __builtin_amdgcn_mfma_f32_16x16x32_bf16(af[mt], bff[nt], acc[mt][nt], 0, 0, 0);
    __syncthreads();
  }

#pragma unroll
  for (int nt = 0; nt < 4; ++nt) {
    int n = nBase + wn + nt * 16 + l16;
    float bv = bias[n];
#pragma unroll
    for (int mt = 0; mt < 4; ++mt) {
#pragma unroll
      for (int j = 0; j < 4; ++j) {
        int m = mBase + wm + mt * 16 + quad * 4 + j;
        out[((size_t)m << 10) + n] = acc[mt][nt][j] + bv;
      }
    }
  }
}

// ---------------------------------------------------------------------------
// Memory plan (elem = bf16; 1M = 1<<20 elem = 2 MB):
//  ws (32 MB = 16M elem): w4 [0,4M) | k [4M,8M) | vT [8M,12M) | q [12M,16M)
//    - lbuf (fp32, 512 KB) overlays [0,256K elem) — wq dead by then
//    - ctx [12M,16M) overlays q after attn (q dead)
//  d_out (16 MB = 8M elem bf16 view): xqb [0,4M) | xkvb [4M,8M)
//    - attn partials OA [0,4M), OB [4M,8M) overlay (xqb/xkvb dead)
//    - final fp32 out overwrites everything (partials dead)
// All phases are stream-ordered; no region is concurrently read+written.
// ---------------------------------------------------------------------------
extern "C" void kernel_launch(void* const* d_in, const int* in_sizes, int n_in,
                              void* d_out, int out_size, void* d_ws, size_t ws_size,
                              hipStream_t stream) {
  const float* x_q  = (const float*)d_in[0];
  const float* x_kv = (const float*)d_in[1];
  const float* wq   = (const float*)d_in[2];
  const float* bq   = (const float*)d_in[3];
  const float* wk   = (const float*)d_in[4];
  const float* bk   = (const float*)d_in[5];
  const float* wv   = (const float*)d_in[6];
  const float* bv   = (const float*)d_in[7];
  const float* wo   = (const float*)d_in[8];
  const float* bo   = (const float*)d_in[9];

  unsigned short* base = (unsigned short*)d_ws;
  unsigned short* ob   = (unsigned short*)d_out;

  unsigned short* wob  = base + (3u << 20);
  unsigned short* k    = base + (4u << 20);
  unsigned short* vT   = base + (8u << 20);
  unsigned short* q    = base + (12u << 20);
  unsigned short* ctx  = q;                    // overlays q after attn
  float*          lbuf = (float*)d_ws;         // overlays wq (dead)
  unsigned short* xqb  = ob;
  unsigned short* xkvb = ob + (4u << 20);
  unsigned short* Opart = ob;                  // overlays xqb/xkvb (dead)
  float* out = (float*)d_out;

  cvt8<<<12288, 256, 0, stream>>>(wq, wk, wv, wo, x_q, x_kv, base, ob);
  gemm_qkv_bf<<<dim3(8, 32, 3), 256, 0, stream>>>(xqb, xkvb, base,
                                                  bq, bk, bv, q, k, vT);
  rope_kernel<<<16384, 256, 0, stream>>>(q, k);
  attn_v6<<<1024, 256, 0, stream>>>(q, k, vT, Opart, lbuf);
  combine_kernel<<<8192, 256, 0, stream>>>(Opart, lbuf, ctx);
  gemm_o_bf<<<dim3(8, 32), 256, 0, stream>>>(ctx, wob, bo, out);
}